// Round 2
// 158.747 us; speedup vs baseline: 1.0263x; 1.0263x over previous
//
#include <hip/hip_runtime.h>
#include <math.h>

// InterpolatorMask: out = sum(roll(mask, ind) * yOrig), ind = floor((x-x0)/dx),
// zeroed when x outside [x0, xMax). Equivalently:
//   out = sum_j mask[j] * yOrig[(j + ind) mod N]
// Memory-bound. Exact-zero skip: mask[j]==0 contributes exactly 0 (y finite),
// so we only stream mask (64 MiB) and gather y solely where mask != 0.
//
// R1/R2: grid-stride stream (2048 blocks x 256 thr = 8 blocks/CU = 32 waves/CU,
// max occupancy) instead of a one-shot 16384-block launch; nontemporal mask
// loads (read-once stream, no reuse to preserve — harness fills evict L3
// between iterations anyway). R2: use clang ext_vector_type for the
// nontemporal builtin (HIP float4 is a class type the builtin rejects).

typedef float f32x4 __attribute__((ext_vector_type(4)));

__global__ __launch_bounds__(256) void interp_mask_reduce(
    const float* __restrict__ xp,
    const float* __restrict__ xOrig,
    const float* __restrict__ yOrig,
    const float* __restrict__ mask,
    float* __restrict__ out,
    int n)
{
    // Scalar params — broadcast loads, L1/L2-cached, negligible traffic.
    const float xv   = xp[0];
    const float x0   = xOrig[0];
    const float dx   = xOrig[1] - xOrig[0];
    const float xMax = xOrig[n - 1];
    const float scale = (xv >= x0 && xv < xMax) ? 1.0f : 0.0f;
    const int   ind   = (int)floorf((xv - x0) / dx);

    float acc = 0.0f;
    const int n4     = n >> 2;                        // full float4 groups
    const int tid    = blockIdx.x * blockDim.x + threadIdx.x;
    const int stride = gridDim.x * blockDim.x;
    const f32x4* m4  = reinterpret_cast<const f32x4*>(mask);

    for (int i = tid; i < n4; i += stride) {
        const f32x4 m = __builtin_nontemporal_load(m4 + i);
        // Wave-uniform almost everywhere: only the first few waves see nonzero
        // mask, so the y-gather (and its HBM traffic) is skipped for ~100% of
        // the grid.
        if (m.x != 0.0f || m.y != 0.0f || m.z != 0.0f || m.w != 0.0f) {
            long long i0 = (long long)i * 4 + (long long)ind;
            i0 %= (long long)n;
            if (i0 < 0) i0 += n;
            int j0 = (int)i0;
            int j1 = j0 + 1; if (j1 >= n) j1 -= n;
            int j2 = j1 + 1; if (j2 >= n) j2 -= n;
            int j3 = j2 + 1; if (j3 >= n) j3 -= n;
            acc += m.x * yOrig[j0] + m.y * yOrig[j1]
                 + m.z * yOrig[j2] + m.w * yOrig[j3];
        }
    }

    // Scalar tail for n not divisible by 4 (n = 2^24 in the bench: no-op).
    if (tid == 0) {
        for (int j = (n4 << 2); j < n; ++j) {
            const float mv = mask[j];
            if (mv != 0.0f) {
                long long i0 = (long long)j + (long long)ind;
                i0 %= (long long)n;
                if (i0 < 0) i0 += n;
                acc += mv * yOrig[(int)i0];
            }
        }
    }

    acc *= scale;

    // wave64 butterfly reduction
    #pragma unroll
    for (int off = 32; off > 0; off >>= 1)
        acc += __shfl_down(acc, off, 64);

    // One atomic per wave with a nonzero partial (≈1 total across the grid).
    // Adding exact zeros in any order is exact, so atomic ordering is benign.
    if ((threadIdx.x & 63) == 0 && acc != 0.0f)
        atomicAdd(out, acc);
}

extern "C" void kernel_launch(void* const* d_in, const int* in_sizes, int n_in,
                              void* d_out, int out_size, void* d_ws, size_t ws_size,
                              hipStream_t stream) {
    const float* x     = (const float*)d_in[0];
    const float* xOrig = (const float*)d_in[1];
    const float* yOrig = (const float*)d_in[2];
    const float* mask  = (const float*)d_in[3];
    float* out = (float*)d_out;
    const int n = in_sizes[1];  // length of xOrig / yOrig / mask

    // d_out is poisoned to 0xAA before every timed launch — zero it on-stream
    // (hipMemsetAsync is graph-capture safe).
    (void)hipMemsetAsync(d_out, 0, sizeof(float), stream);

    const int threads = 256;
    int blocks = ((n >> 2) + threads - 1) / threads;
    if (blocks > 2048) blocks = 2048;   // 8 blocks/CU on 256 CUs, grid-stride
    if (blocks < 1)    blocks = 1;
    interp_mask_reduce<<<blocks, threads, 0, stream>>>(x, xOrig, yOrig, mask, out, n);
}